// Round 5
// baseline (237.023 us; speedup 1.0000x reference)
//
#include <hip/hip_runtime.h>
#include <hip/hip_cooperative_groups.h>
#include <math.h>

namespace cg = cooperative_groups;

// Problem constants
#define B_    256
#define S_    196
#define DIM_  768
#define D4_   192          // DIM/4
#define POOL_ 1024
#define LEN_  8
#define TOPK_ 8

// Output layout (fp32, concatenated flat in return order)
#define RS_OFF     51118080L
#define SIM_OFF    51118081L
#define IDX_OFF    51380225L

// Workspace layout (float offsets)
#define WS_XNORM   0L          // 256*768             = 196608
#define WS_PNORMT  196608L     // 768*1024 transposed = 786432
#define WS_PART    983040L     // 4*256*1024 partials = 1048576
#define WS_ROWIDS  2031616L    // 256*8 int
#define WS_MAJOR   2032128L    // 8 int
// total 8.13 MB (same as round 4, proven to fit)

// ---------------------------------------------------------------------------
// One cooperative kernel, 256 blocks x 1024 threads (1 block/CU).
// Phase 1: copy+mean+l2norm (t<768) ; prompt_key l2normT (t>=768, 4 rows/blk)
// Phase 2: similarity partials (64 bg x 4 dc) , 4-way d-split per block
// Phase 3: per-row top-8 (block b -> row b, wave 0)
// Phase 4: consensus (block 0): histogram -> top-8 counts -> idx + reduce_sim
// Phase 5: gather 8 major prompts into output head (block b -> batch b)
// ---------------------------------------------------------------------------
__global__ void __launch_bounds__(1024, 4) mega_kernel(
        const float4* __restrict__ x4,
        const float4* __restrict__ pk4,
        const float4* __restrict__ prompt4,
        float4* __restrict__ out4,
        float4* __restrict__ xnorm4,
        float*  __restrict__ pT,
        float4* __restrict__ part4,
        int*    __restrict__ row_ids,
        int*    __restrict__ major,
        float*  __restrict__ sim,
        float*  __restrict__ idx_out,
        float*  __restrict__ rs_out) {
    cg::grid_group grid = cg::this_grid();

    __shared__ float4 lds_part[768];       // 12 KB (phase 1)
    __shared__ float  sred[192];
    __shared__ float  sscale;
    __shared__ float4 xs4[4 * 48];         // 3 KB  (phase 2)
    __shared__ float4 red4[3 * 4 * 256];   // 48 KB (phase 2)
    __shared__ int    hist[POOL_];         // 4 KB  (phase 4)
    __shared__ int    majs[TOPK_];
    __shared__ float  redc[256];

    const int b = blockIdx.x;
    const int t = threadIdx.x;

    // ===== Phase 1 =====
    float4 m = {0.f, 0.f, 0.f, 0.f};
    if (t < 768) {
        // contiguous copy + mean accumulate for batch row b
        const float4* xr = x4 + (long)b * (S_ * D4_);
        float4* ow = out4 + ((long)b * 260 + 64) * D4_;
        float4 acc = {0.f, 0.f, 0.f, 0.f};
        // 196*192 = 37632 = 49*768 ; (t + k*768) % 192 == t % 192
        #pragma unroll 7
        for (int k = 0; k < 49; ++k) {
            int i = t + k * 768;
            float4 v = xr[i];
            acc.x += v.x; acc.y += v.y; acc.z += v.z; acc.w += v.w;
            ow[i] = v;
        }
        lds_part[t] = acc;
    } else {
        // prompt_key l2norm -> transposed pT ; wave w handles pool row b*4+w
        int w = (t - 768) >> 6, lane = t & 63;
        int r = b * 4 + w;
        const float4* pr = pk4 + (long)r * D4_;
        float4 v0 = pr[lane], v1 = pr[64 + lane], v2 = pr[128 + lane];
        float ss = v0.x*v0.x + v0.y*v0.y + v0.z*v0.z + v0.w*v0.w
                 + v1.x*v1.x + v1.y*v1.y + v1.z*v1.z + v1.w*v1.w
                 + v2.x*v2.x + v2.y*v2.y + v2.z*v2.z + v2.w*v2.w;
        #pragma unroll
        for (int off = 32; off > 0; off >>= 1) ss += __shfl_xor(ss, off);
        float sc = 1.0f / sqrtf(fmaxf(ss, 1e-12f));
        int d0 = 4 * lane;
        pT[(long)(d0 + 0) * POOL_ + r] = v0.x * sc;
        pT[(long)(d0 + 1) * POOL_ + r] = v0.y * sc;
        pT[(long)(d0 + 2) * POOL_ + r] = v0.z * sc;
        pT[(long)(d0 + 3) * POOL_ + r] = v0.w * sc;
        pT[(long)(256 + d0 + 0) * POOL_ + r] = v1.x * sc;
        pT[(long)(256 + d0 + 1) * POOL_ + r] = v1.y * sc;
        pT[(long)(256 + d0 + 2) * POOL_ + r] = v1.z * sc;
        pT[(long)(256 + d0 + 3) * POOL_ + r] = v1.w * sc;
        pT[(long)(512 + d0 + 0) * POOL_ + r] = v2.x * sc;
        pT[(long)(512 + d0 + 1) * POOL_ + r] = v2.y * sc;
        pT[(long)(512 + d0 + 2) * POOL_ + r] = v2.z * sc;
        pT[(long)(512 + d0 + 3) * POOL_ + r] = v2.w * sc;
    }
    __syncthreads();
    if (t < 192) {
        float4 a = lds_part[t], b1 = lds_part[t + 192],
               c1 = lds_part[t + 384], d1 = lds_part[t + 576];
        m.x = (a.x + b1.x + c1.x + d1.x) / 196.f;
        m.y = (a.y + b1.y + c1.y + d1.y) / 196.f;
        m.z = (a.z + b1.z + c1.z + d1.z) / 196.f;
        m.w = (a.w + b1.w + c1.w + d1.w) / 196.f;
        sred[t] = m.x * m.x + m.y * m.y + m.z * m.z + m.w * m.w;
    }
    __syncthreads();
    if (t < 64) {
        float s2 = sred[t] + sred[t + 64] + sred[t + 128];
        #pragma unroll
        for (int off = 32; off > 0; off >>= 1) s2 += __shfl_xor(s2, off);
        if (t == 0) sscale = 1.0f / sqrtf(fmaxf(s2, 1e-12f));
    }
    __syncthreads();
    if (t < 192) {
        float sc = sscale;
        float4 o = {m.x * sc, m.y * sc, m.z * sc, m.w * sc};
        xnorm4[(long)b * D4_ + t] = o;
    }

    grid.sync();

    // ===== Phase 2: similarity partials =====
    {
        int bg = b >> 2, dc = b & 3;
        int p4 = t & 255;       // colquad (4 consecutive pool cols)
        int ds = t >> 8;        // 0..3 quarter of the 192-d chunk (48 d each)
        if (t < 192) {
            int r = t / 48, q = t % 48;
            xs4[t] = xnorm4[(long)(bg * 4 + r) * D4_ + dc * 48 + q];
        }
        __syncthreads();
        float4 a0 = {0,0,0,0}, a1 = {0,0,0,0}, a2 = {0,0,0,0}, a3 = {0,0,0,0};
        int qbase = ds * 12;
        const float4* pT4 = (const float4*)pT;
        const float4* pbase = pT4 + ((long)dc * 192 + ds * 48) * 256 + p4;
        #pragma unroll 3
        for (int q = 0; q < 12; ++q) {
            float4 xa = xs4[qbase + q];
            float4 xb = xs4[48 + qbase + q];
            float4 xc = xs4[96 + qbase + q];
            float4 xd = xs4[144 + qbase + q];
            const float* xaf = (const float*)&xa;
            const float* xbf = (const float*)&xb;
            const float* xcf = (const float*)&xc;
            const float* xdf = (const float*)&xd;
            #pragma unroll
            for (int j = 0; j < 4; ++j) {
                float4 w = pbase[(q * 4 + j) * 256];
                a0.x += xaf[j] * w.x; a0.y += xaf[j] * w.y; a0.z += xaf[j] * w.z; a0.w += xaf[j] * w.w;
                a1.x += xbf[j] * w.x; a1.y += xbf[j] * w.y; a1.z += xbf[j] * w.z; a1.w += xbf[j] * w.w;
                a2.x += xcf[j] * w.x; a2.y += xcf[j] * w.y; a2.z += xcf[j] * w.z; a2.w += xcf[j] * w.w;
                a3.x += xdf[j] * w.x; a3.y += xdf[j] * w.y; a3.z += xdf[j] * w.z; a3.w += xdf[j] * w.w;
            }
        }
        if (ds > 0) {
            int s = ds - 1;
            red4[s * 1024 +        p4] = a0;
            red4[s * 1024 + 256  + p4] = a1;
            red4[s * 1024 + 512  + p4] = a2;
            red4[s * 1024 + 768  + p4] = a3;
        }
        __syncthreads();
        if (ds == 0) {
            #pragma unroll
            for (int s = 0; s < 3; ++s) {
                float4 b0 = red4[s * 1024 +        p4];
                float4 b1 = red4[s * 1024 + 256  + p4];
                float4 b2 = red4[s * 1024 + 512  + p4];
                float4 b3 = red4[s * 1024 + 768  + p4];
                a0.x += b0.x; a0.y += b0.y; a0.z += b0.z; a0.w += b0.w;
                a1.x += b1.x; a1.y += b1.y; a1.z += b1.z; a1.w += b1.w;
                a2.x += b2.x; a2.y += b2.y; a2.z += b2.z; a2.w += b2.w;
                a3.x += b3.x; a3.y += b3.y; a3.z += b3.z; a3.w += b3.w;
            }
            long base = ((long)dc * 256 + bg * 4) * 256 + p4;
            part4[base]       = a0;
            part4[base + 256] = a1;
            part4[base + 512] = a2;
            part4[base + 768] = a3;
        }
    }

    grid.sync();

    // ===== Phase 3: per-row top-8 (block b -> row b, wave 0) =====
    if (t < 64) {
        const float* part = (const float*)part4;
        int row = b, lane = t;
        float v[16];
        #pragma unroll
        for (int j = 0; j < 16; ++j) {
            int p = lane + j * 64;
            float s = part[(long)row * POOL_ + p]
                    + part[(long)(256 + row) * POOL_ + p]
                    + part[(long)(512 + row) * POOL_ + p]
                    + part[(long)(768 + row) * POOL_ + p];
            v[j] = s;
            sim[(long)row * POOL_ + p] = s;
        }
        for (int it = 0; it < TOPK_; ++it) {
            float bv = v[0];
            int   bi = lane;
            #pragma unroll
            for (int j = 1; j < 16; ++j) {
                if (v[j] > bv) { bv = v[j]; bi = lane + j * 64; }  // keep-first => smallest idx
            }
            #pragma unroll
            for (int off = 32; off > 0; off >>= 1) {
                float ov = __shfl_xor(bv, off);
                int   oi = __shfl_xor(bi, off);
                if (ov > bv || (ov == bv && oi < bi)) { bv = ov; bi = oi; }
            }
            if ((bi & 63) == lane) v[bi >> 6] = -INFINITY;
            if (lane == 0) row_ids[row * TOPK_ + it] = bi;
        }
    }

    grid.sync();

    // ===== Phase 4: consensus on block 0 =====
    if (b == 0) {
        hist[t] = 0;
        __syncthreads();
        if (t < 256) {
            #pragma unroll
            for (int j = 0; j < TOPK_; ++j) atomicAdd(&hist[row_ids[t * TOPK_ + j]], 1);
        }
        __syncthreads();
        if (t < 64) {
            int lane = t;
            int v[16];
            #pragma unroll
            for (int j = 0; j < 16; ++j) v[j] = hist[lane + j * 64];
            for (int it = 0; it < TOPK_; ++it) {
                int bv = v[0];
                int bi = lane;
                #pragma unroll
                for (int j = 1; j < 16; ++j) {
                    if (v[j] > bv) { bv = v[j]; bi = lane + j * 64; }
                }
                #pragma unroll
                for (int off = 32; off > 0; off >>= 1) {
                    int ov = __shfl_xor(bv, off);
                    int oi = __shfl_xor(bi, off);
                    if (ov > bv || (ov == bv && oi < bi)) { bv = ov; bi = oi; }
                }
                if (lane == 0) { majs[it] = bi; major[it] = bi; }
                if ((bi & 63) == lane) v[bi >> 6] = -1;
            }
        }
        __syncthreads();
        // idx output [256,8]
        for (int i = t; i < B_ * TOPK_; i += 1024) idx_out[i] = (float)majs[i & 7];
        // reduce_sim
        if (t < 256) {
            float s = 0.f;
            const float* r = sim + (long)t * POOL_;
            #pragma unroll
            for (int k = 0; k < TOPK_; ++k) s += r[majs[k]];
            redc[t] = s;
        }
        __syncthreads();
        for (int off = 128; off > 0; off >>= 1) {
            if (t < off) redc[t] += redc[t + off];
            __syncthreads();
        }
        if (t == 0) *rs_out = redc[0] / (float)B_;
    }

    grid.sync();

    // ===== Phase 5: gather (block b -> batch b head slice, contiguous) =====
    if (t < TOPK_) majs[t] = major[t];
    __syncthreads();
    {
        float4* dst = out4 + (long)b * 260 * D4_;   // 64*192 = 12288 float4
        #pragma unroll 4
        for (int k = 0; k < 12; ++k) {
            int i = t + k * 1024;
            int kl = i / 192;
            int d4 = i % 192;
            int pid = majs[kl >> 3];
            dst[i] = prompt4[((long)pid * LEN_ + (kl & 7)) * D4_ + d4];
        }
    }
}

// ---------------------------------------------------------------------------
extern "C" void kernel_launch(void* const* d_in, const int* in_sizes, int n_in,
                              void* d_out, int out_size, void* d_ws, size_t ws_size,
                              hipStream_t stream) {
    const float4* x4      = (const float4*)d_in[0];
    const float4* prompt4 = (const float4*)d_in[1];
    const float4* pk4     = (const float4*)d_in[2];
    float* out = (float*)d_out;
    float* ws  = (float*)d_ws;

    float4* out4    = (float4*)out;
    float4* xnorm4  = (float4*)(ws + WS_XNORM);
    float*  pT      = ws + WS_PNORMT;
    float4* part4   = (float4*)(ws + WS_PART);
    int*    row_ids = (int*)(ws + WS_ROWIDS);
    int*    major   = (int*)(ws + WS_MAJOR);
    float*  out_rs  = out + RS_OFF;
    float*  out_sim = out + SIM_OFF;
    float*  out_idx = out + IDX_OFF;

    void* args[] = { (void*)&x4, (void*)&pk4, (void*)&prompt4, (void*)&out4,
                     (void*)&xnorm4, (void*)&pT, (void*)&part4, (void*)&row_ids,
                     (void*)&major, (void*)&out_sim, (void*)&out_idx, (void*)&out_rs };
    hipLaunchCooperativeKernel((const void*)mega_kernel, dim3(256), dim3(1024),
                               args, 0, stream);
}

// Round 6
// 166.981 us; speedup vs baseline: 1.4195x; 1.4195x over previous
//
#include <hip/hip_runtime.h>
#include <math.h>

// Problem constants
#define B_    256
#define S_    196
#define DIM_  768
#define D4_   192          // DIM/4
#define POOL_ 1024
#define LEN_  8
#define TOPK_ 8

// Output layout (fp32, concatenated flat in return order)
#define RS_OFF     51118080L
#define SIM_OFF    51118081L
#define IDX_OFF    51380225L

// Workspace layout (float offsets)
#define WS_XNORM   0L          // 256*768             = 196608
#define WS_PNORMT  196608L     // 768*1024 transposed = 786432
#define WS_PART    983040L     // 4*256*1024 partials = 1048576
#define WS_ROWIDS  2031616L    // 256*8 int
#define WS_MAJOR   2032128L    // 8 int
#define WS_ARRIVE  2032192L    // 1 int (grid barrier counter)

// ---------------------------------------------------------------------------
// Lean device-scope grid barrier (monotonic counter, no reset within launch).
// Safe only when all blocks are co-resident (cooperative launch guarantees).
// ---------------------------------------------------------------------------
__device__ __forceinline__ void grid_barrier(int* arrive, int target) {
    __syncthreads();
    if (threadIdx.x == 0) {
        // release all prior writes, bump arrival count
        __hip_atomic_fetch_add(arrive, 1, __ATOMIC_ACQ_REL, __HIP_MEMORY_SCOPE_AGENT);
        // acquire-spin until all blocks of this phase arrived
        while (__hip_atomic_load(arrive, __ATOMIC_ACQUIRE, __HIP_MEMORY_SCOPE_AGENT) < target) {
            __builtin_amdgcn_s_sleep(2);
        }
    }
    __syncthreads();
}

// ---------------------------------------------------------------------------
// K1: fused prep (identical to round-4's proven kernel) + barrier reset.
// Blocks 0..255: per-batch-row contiguous copy + mean + l2norm.
// Blocks 256..511: prompt_key l2norm -> transposed pnormT (4 rows/block).
// ---------------------------------------------------------------------------
__global__ void __launch_bounds__(768) prep_kernel(
        const float4* __restrict__ x4,
        const float4* __restrict__ pk4,
        float4* __restrict__ out4,
        float4* __restrict__ xnorm4,
        float* __restrict__ pT,
        int* __restrict__ arrive) {
    __shared__ float4 part[768];
    __shared__ float  sred[192];
    __shared__ float  sscale;
    __shared__ float  wss[12];
    int t = threadIdx.x;   // 0..767
    if (blockIdx.x == 0 && t == 0) *arrive = 0;   // reset for node-2 barriers
    if (blockIdx.x < B_) {
        int b = blockIdx.x;
        const float4* xr = x4 + (long)b * (S_ * D4_);          // contiguous 588 KB
        float4* ow = out4 + ((long)b * 260 + 64) * D4_;        // contiguous dest
        float4 acc = {0.f, 0.f, 0.f, 0.f};
        // 196*192 = 37632 = 49*768; (t + k*768) % 192 == t % 192
        #pragma unroll 7
        for (int k = 0; k < 49; ++k) {
            int i = t + k * 768;
            float4 v = xr[i];
            acc.x += v.x; acc.y += v.y; acc.z += v.z; acc.w += v.w;
            ow[i] = v;
        }
        part[t] = acc;
        __syncthreads();
        float4 m = {0.f, 0.f, 0.f, 0.f};
        if (t < 192) {
            float4 a = part[t], b1 = part[t + 192], c1 = part[t + 384], d1 = part[t + 576];
            m.x = (a.x + b1.x + c1.x + d1.x) / 196.f;
            m.y = (a.y + b1.y + c1.y + d1.y) / 196.f;
            m.z = (a.z + b1.z + c1.z + d1.z) / 196.f;
            m.w = (a.w + b1.w + c1.w + d1.w) / 196.f;
            sred[t] = m.x * m.x + m.y * m.y + m.z * m.z + m.w * m.w;
        }
        __syncthreads();
        if (t < 64) {
            float s2 = sred[t] + sred[t + 64] + sred[t + 128];
            #pragma unroll
            for (int off = 32; off > 0; off >>= 1) s2 += __shfl_xor(s2, off);
            if (t == 0) sscale = 1.0f / sqrtf(fmaxf(s2, 1e-12f));
        }
        __syncthreads();
        if (t < 192) {
            float sc = sscale;
            float4 o = {m.x * sc, m.y * sc, m.z * sc, m.w * sc};
            xnorm4[(long)b * D4_ + t] = o;
        }
    } else {
        int r0 = (blockIdx.x - B_) * 4;
        int g = t / 192, i = t % 192;   // group 0..3 == waves [3g,3g+2]
        int r = r0 + g;
        float4 v = pk4[(long)r * D4_ + i];
        float ss = v.x * v.x + v.y * v.y + v.z * v.z + v.w * v.w;
        #pragma unroll
        for (int off = 32; off > 0; off >>= 1) ss += __shfl_xor(ss, off);
        if ((t & 63) == 0) wss[t >> 6] = ss;
        __syncthreads();
        float tot = wss[3 * g] + wss[3 * g + 1] + wss[3 * g + 2];
        float sc = 1.0f / sqrtf(fmaxf(tot, 1e-12f));
        int d = i * 4;
        pT[(long)d       * POOL_ + r] = v.x * sc;
        pT[(long)(d + 1) * POOL_ + r] = v.y * sc;
        pT[(long)(d + 2) * POOL_ + r] = v.z * sc;
        pT[(long)(d + 3) * POOL_ + r] = v.w * sc;
    }
}

// ---------------------------------------------------------------------------
// K2: cooperative "rest" kernel, 256 blocks x 512 threads, 1 block/CU.
// Phase A: similarity partials (round-4 simpart internals; bg=b>>2, dc=b&3)
// Phase B: per-row top-8 (block b -> row b, wave 0)
// Phase C: consensus (block 0): histogram -> top-8 counts -> idx + reduce_sim
// Phase D: gather 8 major prompts into output head (block b -> batch b)
// ---------------------------------------------------------------------------
__global__ void __launch_bounds__(512) rest_kernel(
        const float4* __restrict__ xnorm4,
        const float*  __restrict__ pT,
        const float4* __restrict__ prompt4,
        float4* __restrict__ out4,
        float4* __restrict__ part4,
        int*    __restrict__ row_ids,
        int*    __restrict__ major,
        float*  __restrict__ sim,
        float*  __restrict__ idx_out,
        float*  __restrict__ rs_out,
        int*    __restrict__ arrive) {
    __shared__ float4 xs4[4 * 48];      // 3 KB
    __shared__ float4 red4[4 * 256];    // 16 KB
    __shared__ int    hist[POOL_];      // 4 KB
    __shared__ int    majs[TOPK_];
    __shared__ float  redc[256];

    const int b = blockIdx.x;
    const int t = threadIdx.x;

    // ===== Phase A: simpart (identical math to round-4 simpart) =====
    {
        int bg = b >> 2, dc = b & 3;
        int p4 = t & 255;        // colquad: cols 4*p4..4*p4+3
        int ds = t >> 8;         // 0/1 half of the 192-d chunk
        if (t < 192) {
            int r = t / 48, q = t % 48;
            xs4[r * 48 + q] = xnorm4[(long)(bg * 4 + r) * D4_ + dc * 48 + q];
        }
        __syncthreads();
        float4 a0 = {0,0,0,0}, a1 = {0,0,0,0}, a2 = {0,0,0,0}, a3 = {0,0,0,0};
        int qbase = ds * 24;
        const float4* pT4 = (const float4*)pT;
        const float4* pbase = pT4 + ((long)dc * 192 + ds * 96) * 256 + p4;
        #pragma unroll 2
        for (int q = 0; q < 24; ++q) {
            float4 xa = xs4[qbase + q];
            float4 xb = xs4[48 + qbase + q];
            float4 xc = xs4[96 + qbase + q];
            float4 xd = xs4[144 + qbase + q];
            const float* xaf = (const float*)&xa;
            const float* xbf = (const float*)&xb;
            const float* xcf = (const float*)&xc;
            const float* xdf = (const float*)&xd;
            #pragma unroll
            for (int j = 0; j < 4; ++j) {
                float4 w = pbase[(q * 4 + j) * 256];
                a0.x += xaf[j] * w.x; a0.y += xaf[j] * w.y; a0.z += xaf[j] * w.z; a0.w += xaf[j] * w.w;
                a1.x += xbf[j] * w.x; a1.y += xbf[j] * w.y; a1.z += xbf[j] * w.z; a1.w += xbf[j] * w.w;
                a2.x += xcf[j] * w.x; a2.y += xcf[j] * w.y; a2.z += xcf[j] * w.z; a2.w += xcf[j] * w.w;
                a3.x += xdf[j] * w.x; a3.y += xdf[j] * w.y; a3.z += xdf[j] * w.z; a3.w += xdf[j] * w.w;
            }
        }
        if (ds == 1) {
            red4[p4]       = a0;
            red4[256 + p4] = a1;
            red4[512 + p4] = a2;
            red4[768 + p4] = a3;
        }
        __syncthreads();
        if (ds == 0) {
            float4 b0 = red4[p4], b1 = red4[256 + p4], b2 = red4[512 + p4], b3 = red4[768 + p4];
            a0.x += b0.x; a0.y += b0.y; a0.z += b0.z; a0.w += b0.w;
            a1.x += b1.x; a1.y += b1.y; a1.z += b1.z; a1.w += b1.w;
            a2.x += b2.x; a2.y += b2.y; a2.z += b2.z; a2.w += b2.w;
            a3.x += b3.x; a3.y += b3.y; a3.z += b3.z; a3.w += b3.w;
            long base = ((long)dc * 256 + bg * 4) * 256 + p4;
            part4[base]       = a0;
            part4[base + 256] = a1;
            part4[base + 512] = a2;
            part4[base + 768] = a3;
        }
    }

    grid_barrier(arrive, 256);

    // ===== Phase B: per-row top-8 (block b -> row b, wave 0) =====
    if (t < 64) {
        const float* part = (const float*)part4;
        int row = b, lane = t;
        float v[16];
        #pragma unroll
        for (int j = 0; j < 16; ++j) {
            int p = lane + j * 64;
            float s = part[(long)row * POOL_ + p]
                    + part[(long)(256 + row) * POOL_ + p]
                    + part[(long)(512 + row) * POOL_ + p]
                    + part[(long)(768 + row) * POOL_ + p];
            v[j] = s;
            sim[(long)row * POOL_ + p] = s;
        }
        for (int it = 0; it < TOPK_; ++it) {
            float bv = v[0];
            int   bi = lane;
            #pragma unroll
            for (int j = 1; j < 16; ++j) {
                if (v[j] > bv) { bv = v[j]; bi = lane + j * 64; }  // keep-first => smallest idx
            }
            #pragma unroll
            for (int off = 32; off > 0; off >>= 1) {
                float ov = __shfl_xor(bv, off);
                int   oi = __shfl_xor(bi, off);
                if (ov > bv || (ov == bv && oi < bi)) { bv = ov; bi = oi; }
            }
            if ((bi & 63) == lane) v[bi >> 6] = -INFINITY;
            if (lane == 0) row_ids[row * TOPK_ + it] = bi;
        }
    }

    grid_barrier(arrive, 512);

    // ===== Phase C: consensus on block 0 =====
    if (b == 0) {
        hist[t] = 0; hist[t + 512] = 0;
        __syncthreads();
        if (t < 256) {
            #pragma unroll
            for (int j = 0; j < TOPK_; ++j) atomicAdd(&hist[row_ids[t * TOPK_ + j]], 1);
        }
        __syncthreads();
        if (t < 64) {
            int lane = t;
            int v[16];
            #pragma unroll
            for (int j = 0; j < 16; ++j) v[j] = hist[lane + j * 64];
            for (int it = 0; it < TOPK_; ++it) {
                int bv = v[0];
                int bi = lane;
                #pragma unroll
                for (int j = 1; j < 16; ++j) {
                    if (v[j] > bv) { bv = v[j]; bi = lane + j * 64; }
                }
                #pragma unroll
                for (int off = 32; off > 0; off >>= 1) {
                    int ov = __shfl_xor(bv, off);
                    int oi = __shfl_xor(bi, off);
                    if (ov > bv || (ov == bv && oi < bi)) { bv = ov; bi = oi; }
                }
                if (lane == 0) { majs[it] = bi; major[it] = bi; }
                if ((bi & 63) == lane) v[bi >> 6] = -1;
            }
        }
        __syncthreads();
        for (int i = t; i < B_ * TOPK_; i += 512) idx_out[i] = (float)majs[i & 7];
        if (t < 256) {
            float s = 0.f;
            const float* r = sim + (long)t * POOL_;
            #pragma unroll
            for (int k = 0; k < TOPK_; ++k) s += r[majs[k]];
            redc[t] = s;
        }
        __syncthreads();
        for (int off = 128; off > 0; off >>= 1) {
            if (t < off) redc[t] += redc[t + off];
            __syncthreads();
        }
        if (t == 0) *rs_out = redc[0] / (float)B_;
    }

    grid_barrier(arrive, 768);

    // ===== Phase D: gather (block b -> batch b head slice, contiguous) =====
    if (t < TOPK_) majs[t] = major[t];
    __syncthreads();
    {
        float4* dst = out4 + (long)b * 260 * D4_;   // 64*192 = 12288 float4
        #pragma unroll 4
        for (int k = 0; k < 24; ++k) {
            int i = t + k * 512;
            int kl = i / 192;
            int d4 = i % 192;
            int pid = majs[kl >> 3];
            dst[i] = prompt4[((long)pid * LEN_ + (kl & 7)) * D4_ + d4];
        }
    }
}

// ---------------------------------------------------------------------------
extern "C" void kernel_launch(void* const* d_in, const int* in_sizes, int n_in,
                              void* d_out, int out_size, void* d_ws, size_t ws_size,
                              hipStream_t stream) {
    const float4* x4      = (const float4*)d_in[0];
    const float4* prompt4 = (const float4*)d_in[1];
    const float4* pk4     = (const float4*)d_in[2];
    float* out = (float*)d_out;
    float* ws  = (float*)d_ws;

    float4* out4    = (float4*)out;
    float4* xnorm4  = (float4*)(ws + WS_XNORM);
    float*  pT      = ws + WS_PNORMT;
    float4* part4   = (float4*)(ws + WS_PART);
    int*    row_ids = (int*)(ws + WS_ROWIDS);
    int*    major   = (int*)(ws + WS_MAJOR);
    int*    arrive  = (int*)(ws + WS_ARRIVE);
    float*  out_rs  = out + RS_OFF;
    float*  out_sim = out + SIM_OFF;
    float*  out_idx = out + IDX_OFF;

    // Node 1: prep (copy+mean+l2norm, pk l2normT) + barrier-counter reset
    prep_kernel<<<512, 768, 0, stream>>>(x4, pk4, out4, xnorm4, pT, arrive);

    // Node 2: everything else, with lean hand-rolled grid barriers.
    // Cooperative launch used ONLY for the co-residency guarantee.
    const float* pTc = pT;
    void* args[] = { (void*)&xnorm4, (void*)&pTc, (void*)&prompt4, (void*)&out4,
                     (void*)&part4, (void*)&row_ids, (void*)&major,
                     (void*)&out_sim, (void*)&out_idx, (void*)&out_rs,
                     (void*)&arrive };
    hipLaunchCooperativeKernel((const void*)rest_kernel, dim3(256), dim3(512),
                               args, 0, stream);
}

// Round 7
// 129.208 us; speedup vs baseline: 1.8344x; 1.2923x over previous
//
#include <hip/hip_runtime.h>
#include <math.h>

// Problem constants
#define B_    256
#define S_    196
#define DIM_  768
#define D4_   192          // DIM/4
#define POOL_ 1024
#define LEN_  8
#define TOPK_ 8

// Output layout (fp32, concatenated flat in return order)
#define RS_OFF     51118080L
#define SIM_OFF    51118081L
#define IDX_OFF    51380225L

// Workspace layout (float offsets)
#define WS_XNORM   0L          // 256*768             = 196608
#define WS_PNORMT  196608L     // 768*1024 transposed = 786432
#define WS_ROWIDS  983040L     // 256*8 int           = 2048
#define WS_MAJOR   985088L     // 8 int
#define WS_ROOT    985096L     // 1 int (last-block counter)

// ---------------------------------------------------------------------------
// K1: fused prep (proven round-4 kernel) + root-counter reset.
// Blocks 0..255: per-batch-row contiguous copy + mean + l2norm.
// Blocks 256..511: prompt_key l2norm -> transposed pnormT (4 rows/block).
// ---------------------------------------------------------------------------
__global__ void __launch_bounds__(768) prep_kernel(
        const float4* __restrict__ x4,
        const float4* __restrict__ pk4,
        float4* __restrict__ out4,
        float4* __restrict__ xnorm4,
        float* __restrict__ pT,
        int* __restrict__ root) {
    __shared__ float4 part[768];
    __shared__ float  sred[192];
    __shared__ float  sscale;
    __shared__ float  wss[12];
    int t = threadIdx.x;   // 0..767
    if (blockIdx.x == 0 && t == 0) *root = 0;   // reset last-block counter
    if (blockIdx.x < B_) {
        int b = blockIdx.x;
        const float4* xr = x4 + (long)b * (S_ * D4_);          // contiguous 588 KB
        float4* ow = out4 + ((long)b * 260 + 64) * D4_;        // contiguous dest
        float4 acc = {0.f, 0.f, 0.f, 0.f};
        // 196*192 = 37632 = 49*768; (t + k*768) % 192 == t % 192
        #pragma unroll 7
        for (int k = 0; k < 49; ++k) {
            int i = t + k * 768;
            float4 v = xr[i];
            acc.x += v.x; acc.y += v.y; acc.z += v.z; acc.w += v.w;
            ow[i] = v;
        }
        part[t] = acc;
        __syncthreads();
        float4 m = {0.f, 0.f, 0.f, 0.f};
        if (t < 192) {
            float4 a = part[t], b1 = part[t + 192], c1 = part[t + 384], d1 = part[t + 576];
            m.x = (a.x + b1.x + c1.x + d1.x) / 196.f;
            m.y = (a.y + b1.y + c1.y + d1.y) / 196.f;
            m.z = (a.z + b1.z + c1.z + d1.z) / 196.f;
            m.w = (a.w + b1.w + c1.w + d1.w) / 196.f;
            sred[t] = m.x * m.x + m.y * m.y + m.z * m.z + m.w * m.w;
        }
        __syncthreads();
        if (t < 64) {
            float s2 = sred[t] + sred[t + 64] + sred[t + 128];
            #pragma unroll
            for (int off = 32; off > 0; off >>= 1) s2 += __shfl_xor(s2, off);
            if (t == 0) sscale = 1.0f / sqrtf(fmaxf(s2, 1e-12f));
        }
        __syncthreads();
        if (t < 192) {
            float sc = sscale;
            float4 o = {m.x * sc, m.y * sc, m.z * sc, m.w * sc};
            xnorm4[(long)b * D4_ + t] = o;
        }
    } else {
        int r0 = (blockIdx.x - B_) * 4;
        int g = t / 192, i = t % 192;   // group 0..3 == waves [3g,3g+2]
        int r = r0 + g;
        float4 v = pk4[(long)r * D4_ + i];
        float ss = v.x * v.x + v.y * v.y + v.z * v.z + v.w * v.w;
        #pragma unroll
        for (int off = 32; off > 0; off >>= 1) ss += __shfl_xor(ss, off);
        if ((t & 63) == 0) wss[t >> 6] = ss;
        __syncthreads();
        float tot = wss[3 * g] + wss[3 * g + 1] + wss[3 * g + 2];
        float sc = 1.0f / sqrtf(fmaxf(tot, 1e-12f));
        int d = i * 4;
        pT[(long)d       * POOL_ + r] = v.x * sc;
        pT[(long)(d + 1) * POOL_ + r] = v.y * sc;
        pT[(long)(d + 2) * POOL_ + r] = v.z * sc;
        pT[(long)(d + 3) * POOL_ + r] = v.w * sc;
    }
}

// ---------------------------------------------------------------------------
// K2: similarity (FINAL values, no partial buffer). grid = (64 bg, 4 pc),
// block = 512. Block computes rows 4bg..4bg+3 x cols [pc*256, pc*256+256)
// over full D=768, split 8-way across threads (ds), LDS-reduced.
// ---------------------------------------------------------------------------
__global__ void __launch_bounds__(512) sim_kernel(
        const float4* __restrict__ xnorm4,
        const float4* __restrict__ pT4,    // [768][256] float4
        float4* __restrict__ sim4) {       // [256][256] float4
    __shared__ float4 xs4[768];            // 4 rows x 192 quads, 12 KB
    __shared__ float4 red4[7 * 256];       // 7 ds x (4 rows x 64 quads), 28 KB
    int bg = blockIdx.x;     // 0..63
    int pc = blockIdx.y;     // 0..3
    int t  = threadIdx.x;    // 0..511
    int q64 = t & 63;        // col-quad within the 256-col quarter
    int ds  = t >> 6;        // 0..7 d-octant (96 d's each)
    // stage 4 x rows (full 768 d)
    {
        int i = t;
        xs4[i] = xnorm4[(long)(bg * 4 + i / 192) * D4_ + (i % 192)];
        i = t + 512;
        if (i < 768)
            xs4[i] = xnorm4[(long)(bg * 4 + i / 192) * D4_ + (i % 192)];
    }
    __syncthreads();
    float4 a0 = {0,0,0,0}, a1 = {0,0,0,0}, a2 = {0,0,0,0}, a3 = {0,0,0,0};
    const float4* pbase = pT4 + ((long)ds * 96) * 256 + pc * 64 + q64;
    int xq = ds * 24;
    #pragma unroll 3
    for (int q = 0; q < 24; ++q) {
        float4 xa = xs4[xq + q];
        float4 xb = xs4[192 + xq + q];
        float4 xc = xs4[384 + xq + q];
        float4 xd = xs4[576 + xq + q];
        const float* xaf = (const float*)&xa;
        const float* xbf = (const float*)&xb;
        const float* xcf = (const float*)&xc;
        const float* xdf = (const float*)&xd;
        #pragma unroll
        for (int j = 0; j < 4; ++j) {
            float4 w = pbase[(q * 4 + j) * 256];
            a0.x += xaf[j] * w.x; a0.y += xaf[j] * w.y; a0.z += xaf[j] * w.z; a0.w += xaf[j] * w.w;
            a1.x += xbf[j] * w.x; a1.y += xbf[j] * w.y; a1.z += xbf[j] * w.z; a1.w += xbf[j] * w.w;
            a2.x += xcf[j] * w.x; a2.y += xcf[j] * w.y; a2.z += xcf[j] * w.z; a2.w += xcf[j] * w.w;
            a3.x += xdf[j] * w.x; a3.y += xdf[j] * w.y; a3.z += xdf[j] * w.z; a3.w += xdf[j] * w.w;
        }
    }
    if (ds > 0) {
        int s = ds - 1;
        red4[s * 256 +        q64] = a0;
        red4[s * 256 +  64  + q64] = a1;
        red4[s * 256 + 128  + q64] = a2;
        red4[s * 256 + 192  + q64] = a3;
    }
    __syncthreads();
    if (ds == 0) {
        #pragma unroll
        for (int s = 0; s < 7; ++s) {
            float4 b0 = red4[s * 256 +       q64];
            float4 b1 = red4[s * 256 +  64 + q64];
            float4 b2 = red4[s * 256 + 128 + q64];
            float4 b3 = red4[s * 256 + 192 + q64];
            a0.x += b0.x; a0.y += b0.y; a0.z += b0.z; a0.w += b0.w;
            a1.x += b1.x; a1.y += b1.y; a1.z += b1.z; a1.w += b1.w;
            a2.x += b2.x; a2.y += b2.y; a2.z += b2.z; a2.w += b2.w;
            a3.x += b3.x; a3.y += b3.y; a3.z += b3.z; a3.w += b3.w;
        }
        long base = ((long)(bg * 4)) * 256 + pc * 64 + q64;
        sim4[base]           = a0;
        sim4[base + 256]     = a1;
        sim4[base + 512]     = a2;
        sim4[base + 768]     = a3;
    }
}

// ---------------------------------------------------------------------------
// K3: per-row top-8 + spin-free last-block consensus.
// 256 blocks x 64 threads (one wave). Block b -> row b. After writing its
// row_ids, each block does ONE system-scope fetch_add; the 256th arrival
// (acquire) runs the consensus: histogram -> top-8 counts (ties -> smallest
// pool id) -> idx output + reduce_sim. No spinning anywhere.
// ---------------------------------------------------------------------------
__global__ void __launch_bounds__(64) topk_consensus_kernel(
        const float* __restrict__ sim,
        int*   __restrict__ row_ids,
        int*   __restrict__ major,
        float* __restrict__ idx_out,
        float* __restrict__ rs_out,
        int*   __restrict__ root) {
    __shared__ int hist[POOL_];
    __shared__ int majs[TOPK_];
    __shared__ int lastFlag;
    int row  = blockIdx.x;
    int lane = threadIdx.x;      // 64 (one wave)
    {
        float v[16];
        const float* r = sim + (long)row * POOL_;
        #pragma unroll
        for (int j = 0; j < 16; ++j) v[j] = r[lane + j * 64];
        for (int it = 0; it < TOPK_; ++it) {
            float bv = v[0];
            int   bi = lane;
            #pragma unroll
            for (int j = 1; j < 16; ++j) {
                if (v[j] > bv) { bv = v[j]; bi = lane + j * 64; }  // keep-first => smallest idx
            }
            #pragma unroll
            for (int off = 32; off > 0; off >>= 1) {
                float ov = __shfl_xor(bv, off);
                int   oi = __shfl_xor(bi, off);
                if (ov > bv || (ov == bv && oi < bi)) { bv = ov; bi = oi; }
            }
            if ((bi & 63) == lane) v[bi >> 6] = -INFINITY;
            if (lane == 0) row_ids[row * TOPK_ + it] = bi;
        }
    }
    // one wave: row_ids writes are from this wave; the release in the RMW
    // (s_waitcnt + L2 writeback at system scope) orders them.
    if (lane == 0) {
        int prev = __hip_atomic_fetch_add(root, 1, __ATOMIC_ACQ_REL,
                                          __HIP_MEMORY_SCOPE_SYSTEM);
        lastFlag = (prev == B_ - 1);
    }
    __syncthreads();
    if (!lastFlag) return;

    // ----- consensus (single wave, fresh caches after system acquire) -----
    #pragma unroll
    for (int j = 0; j < 16; ++j) hist[lane + j * 64] = 0;
    __syncthreads();
    #pragma unroll
    for (int rr = 0; rr < 4; ++rr) {
        int r = lane + rr * 64;
        #pragma unroll
        for (int j = 0; j < TOPK_; ++j) atomicAdd(&hist[row_ids[r * TOPK_ + j]], 1);
    }
    __syncthreads();
    {
        int v[16];
        #pragma unroll
        for (int j = 0; j < 16; ++j) v[j] = hist[lane + j * 64];
        for (int it = 0; it < TOPK_; ++it) {
            int bv = v[0];
            int bi = lane;
            #pragma unroll
            for (int j = 1; j < 16; ++j) {
                if (v[j] > bv) { bv = v[j]; bi = lane + j * 64; }
            }
            #pragma unroll
            for (int off = 32; off > 0; off >>= 1) {
                int ov = __shfl_xor(bv, off);
                int oi = __shfl_xor(bi, off);
                if (ov > bv || (ov == bv && oi < bi)) { bv = ov; bi = oi; }
            }
            if (lane == 0) { majs[it] = bi; major[it] = bi; }
            if ((bi & 63) == lane) v[bi >> 6] = -1;
        }
    }
    __syncthreads();
    // idx output: [256,8]
    #pragma unroll
    for (int k = 0; k < 32; ++k) {
        int i = lane + k * 64;
        idx_out[i] = (float)majs[i & 7];
    }
    // reduce_sim: lane sums rows {lane, lane+64, lane+128, lane+192}
    float s = 0.f;
    #pragma unroll
    for (int rr = 0; rr < 4; ++rr) {
        const float* r = sim + (long)(lane + rr * 64) * POOL_;
        #pragma unroll
        for (int k = 0; k < TOPK_; ++k) s += r[majs[k]];
    }
    #pragma unroll
    for (int off = 32; off > 0; off >>= 1) s += __shfl_xor(s, off);
    if (lane == 0) *rs_out = s / (float)B_;
}

// ---------------------------------------------------------------------------
// K4: gather the 8 major prompts -> prompted_embedding[:, 0:64, :]
// grid-stride over 256*64*192 float4s (proven round-4 kernel).
// ---------------------------------------------------------------------------
__global__ void gather_kernel(const float4* __restrict__ prompt4,
                              const int* __restrict__ major,
                              float4* __restrict__ out4) {
    __shared__ int maj[TOPK_];
    if (threadIdx.x < TOPK_) maj[threadIdx.x] = major[threadIdx.x];
    __syncthreads();
    const long total = (long)B_ * 64 * D4_;
    for (long g = (long)blockIdx.x * blockDim.x + threadIdx.x; g < total;
         g += (long)gridDim.x * blockDim.x) {
        int  d4 = (int)(g % D4_);
        long q  = g / D4_;
        int  kl = (int)(q & 63);
        int  b  = (int)(q >> 6);
        int  pid = maj[kl >> 3];
        int  l   = kl & 7;
        out4[((long)b * 260 + kl) * D4_ + d4] = prompt4[((long)pid * LEN_ + l) * D4_ + d4];
    }
}

// ---------------------------------------------------------------------------
extern "C" void kernel_launch(void* const* d_in, const int* in_sizes, int n_in,
                              void* d_out, int out_size, void* d_ws, size_t ws_size,
                              hipStream_t stream) {
    const float4* x4      = (const float4*)d_in[0];
    const float4* prompt4 = (const float4*)d_in[1];
    const float4* pk4     = (const float4*)d_in[2];
    float* out = (float*)d_out;
    float* ws  = (float*)d_ws;

    float4* out4    = (float4*)out;
    float4* xnorm4  = (float4*)(ws + WS_XNORM);
    float*  pT      = ws + WS_PNORMT;
    int*    row_ids = (int*)(ws + WS_ROWIDS);
    int*    major   = (int*)(ws + WS_MAJOR);
    int*    root    = (int*)(ws + WS_ROOT);
    float*  out_rs  = out + RS_OFF;
    float*  out_sim = out + SIM_OFF;
    float*  out_idx = out + IDX_OFF;

    // Node 1: prep (copy+mean+l2norm, pk l2normT) + root-counter reset
    prep_kernel<<<512, 768, 0, stream>>>(x4, pk4, out4, xnorm4, pT, root);
    // Node 2: final similarity, whole chip, no partial buffer
    dim3 sg(64, 4);
    sim_kernel<<<sg, 512, 0, stream>>>(xnorm4, (const float4*)pT, (float4*)out_sim);
    // Node 3: per-row top-8 + last-block consensus (spin-free)
    topk_consensus_kernel<<<B_, 64, 0, stream>>>(out_sim, row_ids, major,
                                                 out_idx, out_rs, root);
    // Node 4: gather prompts into output head
    gather_kernel<<<2048, 256, 0, stream>>>(prompt4, major, out4);
}